// Round 1
// baseline (245.833 us; speedup 1.0000x reference)
//
#include <hip/hip_runtime.h>

#define SCALE 0.0625f  // C^-0.5 = 1/16

// ---------------------------------------------------------------------------
// prep1: blocks 0..15  -> q[b,c] = TO[b] . Wq[c] + bq[c]      (q in ws)
//        blocks 16..31 -> WvT[o][co] = Wv[co][o]  (64x64 LDS tile transpose)
// ---------------------------------------------------------------------------
__global__ __launch_bounds__(256) void prep1_kernel(
    const float* __restrict__ TO,    // [2,1024]
    const float* __restrict__ Wq,    // [256,1024]
    const float* __restrict__ bq,    // [256]
    const float* __restrict__ Wv,    // [256,256]
    float* __restrict__ qbuf,        // [2,256]
    float* __restrict__ WvT)         // [256,256]
{
    const int blk = blockIdx.x;
    const int t   = threadIdx.x;
    if (blk < 16) {
        const int b    = blk >> 3;
        const int rblk = blk & 7;
        const int wv = t >> 6, l = t & 63;
        const float4* Wq4 = (const float4*)Wq;
        const float4* TO4 = (const float4*)TO;
        for (int rr = 0; rr < 8; ++rr) {
            const int c = rblk * 32 + wv * 8 + rr;
            float acc = 0.f;
#pragma unroll
            for (int i = 0; i < 4; ++i) {
                float4 wq = Wq4[c * 256 + i * 64 + l];
                float4 tv = TO4[b * 256 + i * 64 + l];
                acc = fmaf(wq.x, tv.x, acc);
                acc = fmaf(wq.y, tv.y, acc);
                acc = fmaf(wq.z, tv.z, acc);
                acc = fmaf(wq.w, tv.w, acc);
            }
#pragma unroll
            for (int mask = 1; mask < 64; mask <<= 1)
                acc += __shfl_xor(acc, mask, 64);
            if (l == 0) qbuf[b * 256 + c] = acc + bq[c];
        }
    } else {
        const int idx = blk - 16;
        const int r0 = (idx >> 2) * 64;
        const int c0 = (idx & 3) * 64;
        __shared__ float tile[64][65];
#pragma unroll
        for (int i = 0; i < 16; ++i) {
            int ii = t + 256 * i;
            int r = ii >> 6, c = ii & 63;
            tile[r][c] = Wv[(r0 + r) * 256 + (c0 + c)];
        }
        __syncthreads();
#pragma unroll
        for (int i = 0; i < 16; ++i) {
            int ii = t + 256 * i;
            int rT = ii >> 6, cT = ii & 63;
            WvT[(c0 + rT) * 256 + (r0 + cT)] = tile[cT][rT];
        }
    }
}

// ---------------------------------------------------------------------------
// prep2: 8 blocks: (b, 64-col chunk j) -> qks[b,c'] = SCALE * sum_c q[c] Wk[c][c']
//        block j==0 wave0 also computes qbs[b] = SCALE * q.bk
// ---------------------------------------------------------------------------
__global__ __launch_bounds__(256) void prep2_kernel(
    const float* __restrict__ qbuf,  // [2,256]
    const float* __restrict__ Wk,    // [256,256]
    const float* __restrict__ bk,    // [256]
    float* __restrict__ qks,         // [2,256] (pre-scaled)
    float* __restrict__ qbs)         // [2]     (pre-scaled)
{
    const int blk = blockIdx.x;
    const int t   = threadIdx.x;
    const int b = blk >> 2, j = blk & 3;
    const int cl = t & 63, ck = t >> 6;
    const int cp = 64 * j + cl;
    float partial = 0.f;
    const int cbase = ck * 64;
    for (int cc = 0; cc < 64; ++cc) {
        const int c = cbase + cc;
        partial = fmaf(qbuf[b * 256 + c], Wk[c * 256 + cp], partial);
    }
    __shared__ float r2[4][64];
    r2[ck][cl] = partial;
    __syncthreads();
    if (t < 64) {
        float s = r2[0][t] + r2[1][t] + r2[2][t] + r2[3][t];
        qks[b * 256 + 64 * j + t] = SCALE * s;
    }
    if (j == 0 && ck == 0) {
        float pb = 0.f;
#pragma unroll
        for (int k = 0; k < 4; ++k)
            pb = fmaf(qbuf[b * 256 + cl + 64 * k], bk[cl + 64 * k], pb);
#pragma unroll
        for (int mask = 1; mask < 64; mask <<= 1)
            pb += __shfl_xor(pb, mask, 64);
        if (cl == 0) qbs[b] = SCALE * pb;
    }
}

// ---------------------------------------------------------------------------
// main: 512 blocks x 256 thr. Block = (b, 16-pixel tile). Single pass over x:
//   thread t -> pixel quartet p4 = t&3 (pixels 4*p4..4*p4+3),
//               channels  c = (t>>2) + 64k, k=0..3   (strided, 4 per thread)
//   score partial during global load (x never staged to LDS);
//   shfl_xor butterfly (16 cg/wave) + 512B LDS cross-wave reduce;
//   online softmax over m; wx accumulated from the loaded registers.
// Epilogue: wx -> LDS (stride 20 pad), 4x4-tiled fp32 conv vs WvT + bv.
// ---------------------------------------------------------------------------
__global__ __launch_bounds__(256) void main_kernel(
    const float* __restrict__ X,     // [2,16,256,4096]
    const float* __restrict__ qks,   // [2,256]
    const float* __restrict__ qbs,   // [2]
    const float* __restrict__ WvT,   // [256,256] (WvT[o][co] = Wv[co][o])
    const float* __restrict__ bv,    // [256]
    float* __restrict__ out)         // [2,256,4096]
{
    const int t   = threadIdx.x;
    const int blk = blockIdx.x;
    const int b   = blk >> 8;
    const int hw0 = (blk & 255) << 4;   // 16 pixels per block
    const int p4  = t & 3;
    const int cg  = t >> 2;             // 0..63
    const int l   = t & 63;
    const int wv  = t >> 6;

    float qk[4];
#pragma unroll
    for (int k = 0; k < 4; ++k) qk[k] = qks[b * 256 + cg + 64 * k];
    const float qb = qbs[b];

    float4 wx[4];
#pragma unroll
    for (int k = 0; k < 4; ++k) wx[k] = make_float4(0.f, 0.f, 0.f, 0.f);
    float m_run[4], l_run[4];
#pragma unroll
    for (int i = 0; i < 4; ++i) { m_run[i] = -1e30f; l_run[i] = 0.f; }

    __shared__ __align__(16) float red[2][4][4][4];   // [buf][wave][p4][i]
    __shared__ __align__(16) float slab2[256 * 20];   // wx, stride 20 pad

    const float4* X4 = (const float4*)X;
    const int pixbase = (hw0 >> 2) + p4;

    for (int m = 0; m < 16; ++m) {
        const int mbase = (b * 16 + m) * 256 * 1024 + pixbase;
        float4 v[4];
#pragma unroll
        for (int k = 0; k < 4; ++k)
            v[k] = X4[mbase + (cg + 64 * k) * 1024];

        float sx = 0.f, sy = 0.f, sz = 0.f, sw = 0.f;
#pragma unroll
        for (int k = 0; k < 4; ++k) {
            sx = fmaf(qk[k], v[k].x, sx);
            sy = fmaf(qk[k], v[k].y, sy);
            sz = fmaf(qk[k], v[k].z, sz);
            sw = fmaf(qk[k], v[k].w, sw);
        }
#pragma unroll
        for (int mask = 4; mask < 64; mask <<= 1) {
            sx += __shfl_xor(sx, mask, 64);
            sy += __shfl_xor(sy, mask, 64);
            sz += __shfl_xor(sz, mask, 64);
            sw += __shfl_xor(sw, mask, 64);
        }
        const int buf = m & 1;
        if ((l >> 2) == 0) {   // lanes 0..3 of each wave; lane's p4 == l
            *(float4*)&red[buf][wv][p4][0] = make_float4(sx, sy, sz, sw);
        }
        __syncthreads();
        const float4* rp = (const float4*)&red[buf][0][0][0];
        float4 r0 = rp[0 * 4 + p4];
        float4 r1 = rp[1 * 4 + p4];
        float4 r2_ = rp[2 * 4 + p4];
        float4 r3 = rp[3 * 4 + p4];
        float s[4];
        s[0] = r0.x + r1.x + r2_.x + r3.x + qb;
        s[1] = r0.y + r1.y + r2_.y + r3.y + qb;
        s[2] = r0.z + r1.z + r2_.z + r3.z + qb;
        s[3] = r0.w + r1.w + r2_.w + r3.w + qb;

        float al[4], w[4];
#pragma unroll
        for (int i = 0; i < 4; ++i) {
            const float mn = fmaxf(m_run[i], s[i]);
            al[i] = __expf(m_run[i] - mn);
            w[i]  = __expf(s[i] - mn);
            l_run[i] = fmaf(l_run[i], al[i], w[i]);
            m_run[i] = mn;
        }
#pragma unroll
        for (int k = 0; k < 4; ++k) {
            wx[k].x = fmaf(wx[k].x, al[0], w[0] * v[k].x);
            wx[k].y = fmaf(wx[k].y, al[1], w[1] * v[k].y);
            wx[k].z = fmaf(wx[k].z, al[2], w[2] * v[k].z);
            wx[k].w = fmaf(wx[k].w, al[3], w[3] * v[k].w);
        }
    }

    // normalize + park wx in LDS
    float inv[4];
#pragma unroll
    for (int i = 0; i < 4; ++i) inv[i] = 1.0f / l_run[i];
#pragma unroll
    for (int k = 0; k < 4; ++k) {
        const int c = cg + 64 * k;
        *(float4*)&slab2[c * 20 + 4 * p4] =
            make_float4(wx[k].x * inv[0], wx[k].y * inv[1],
                        wx[k].z * inv[2], wx[k].w * inv[3]);
    }
    __syncthreads();

    // epilogue conv: out[:,co,pix] = bv[co] + sum_o Wv[co][o] * wx[o][pix]
    const int cq = t & 63;     // -> out channels 4*cq..4*cq+3
    const int pq = t >> 6;     // -> pixels 4*pq..4*pq+3
    const float4* WvT4 = (const float4*)WvT;
    const float4  bvv  = ((const float4*)bv)[cq];
    float acc[4][4];
#pragma unroll
    for (int pi = 0; pi < 4; ++pi) {
        acc[0][pi] = bvv.x; acc[1][pi] = bvv.y;
        acc[2][pi] = bvv.z; acc[3][pi] = bvv.w;
    }
#pragma unroll 4
    for (int o = 0; o < 256; ++o) {
        const float4 wv4 = WvT4[o * 64 + cq];
        const float4 xv  = *(const float4*)&slab2[o * 20 + 4 * pq];
        acc[0][0] = fmaf(wv4.x, xv.x, acc[0][0]);
        acc[0][1] = fmaf(wv4.x, xv.y, acc[0][1]);
        acc[0][2] = fmaf(wv4.x, xv.z, acc[0][2]);
        acc[0][3] = fmaf(wv4.x, xv.w, acc[0][3]);
        acc[1][0] = fmaf(wv4.y, xv.x, acc[1][0]);
        acc[1][1] = fmaf(wv4.y, xv.y, acc[1][1]);
        acc[1][2] = fmaf(wv4.y, xv.z, acc[1][2]);
        acc[1][3] = fmaf(wv4.y, xv.w, acc[1][3]);
        acc[2][0] = fmaf(wv4.z, xv.x, acc[2][0]);
        acc[2][1] = fmaf(wv4.z, xv.y, acc[2][1]);
        acc[2][2] = fmaf(wv4.z, xv.z, acc[2][2]);
        acc[2][3] = fmaf(wv4.z, xv.w, acc[2][3]);
        acc[3][0] = fmaf(wv4.w, xv.x, acc[3][0]);
        acc[3][1] = fmaf(wv4.w, xv.y, acc[3][1]);
        acc[3][2] = fmaf(wv4.w, xv.z, acc[3][2]);
        acc[3][3] = fmaf(wv4.w, xv.w, acc[3][3]);
    }
    const int obase = b * 256 * 4096 + hw0 + 4 * pq;
#pragma unroll
    for (int ci = 0; ci < 4; ++ci) {
        const int c = 4 * cq + ci;
        *(float4*)&out[obase + c * 4096] =
            make_float4(acc[ci][0], acc[ci][1], acc[ci][2], acc[ci][3]);
    }
}

// ---------------------------------------------------------------------------
extern "C" void kernel_launch(void* const* d_in, const int* in_sizes, int n_in,
                              void* d_out, int out_size, void* d_ws, size_t ws_size,
                              hipStream_t stream) {
    const float* TO = (const float*)d_in[0];   // [2,1024]
    const float* X  = (const float*)d_in[1];   // [2,16,256,64,64]
    const float* Wq = (const float*)d_in[2];   // [256,1024]
    const float* bq = (const float*)d_in[3];   // [256]
    const float* Wk = (const float*)d_in[4];   // [256,256]
    const float* bk = (const float*)d_in[5];   // [256]
    const float* Wv = (const float*)d_in[6];   // [256,256]
    const float* bv = (const float*)d_in[7];   // [256]
    float* out = (float*)d_out;
    float* ws  = (float*)d_ws;

    float* qbuf = ws;           // 512 floats
    float* qks  = ws + 512;     // 512 floats
    float* qbs  = ws + 1024;    // 2 floats
    float* WvT  = ws + 1088;    // 65536 floats (16B-aligned offset)

    hipLaunchKernelGGL(prep1_kernel, dim3(32), dim3(256), 0, stream,
                       TO, Wq, bq, Wv, qbuf, WvT);
    hipLaunchKernelGGL(prep2_kernel, dim3(8), dim3(256), 0, stream,
                       qbuf, Wk, bk, qks, qbs);
    hipLaunchKernelGGL(main_kernel, dim3(512), dim3(256), 0, stream,
                       X, qks, qbs, WvT, bv, out);
}